// Round 11
// baseline (511.482 us; speedup 1.0000x reference)
//
#include <hip/hip_runtime.h>

// ---------------------------------------------------------------------------
// 2-layer GCN: out = A_norm @ relu(A_norm @ (x@W1) + b1) @ W2 (+b2)
// A_norm = D^-1/2 (A+I) D^-1/2, factored: out[d] = dinv[d]*sum_src(g[src]) + b
// with g = dinv * (x @ W).
//
// R7: 519. R11: 64-ch chunk aggregates [2][N][64] bf16, 509.
// R12: FAILED random atomic scatter. R13: two-phase partition CSR, 495.8.
// R14: XCD-parity chunk pinning: FETCH 320->317 (null) -> agg misses are
//      CAPACITY (12.8 MB WS vs 4 MB L2), not compulsory. Dead-ends measured:
//      16-ch L2-fit = line-slot bound (184 us); src-range phasing = acc
//      traffic >= savings; fp8 = ~0.13 absmax est (vs 0.002) too risky.
// R15: consolidation + de-pollution.
//      (1) srcs CAP-strided; k_build emits row_se[node]=start|end<<32 (u64);
//          global scan (k_bscan) deleted; wprep folded into k_part2.
//      (2) k_part2 single-read: EPT 16, edges reg-cached across phases.
//      (3) aggs: nontemporal loads for srcs/row_se (read-once streams;
//          keep L2 for the gather table).
//      (R15b: nontemporal builtins reject HIP_vector_type (int2) -- pack
//       row_se as u64 scalar. Second occurrence of this lesson.)
// Requires N <= 131072 (17-bit src in packed pairs).
// ---------------------------------------------------------------------------

#define NPB 128          // nodes per bucket (dst >> 7)
#define NBMAX 1024       // supports N <= 131072
#define EPT2 16          // edges per thread in partition kernel
#define PART_TILE2 (256 * EPT2)
#define CAP 5120         // per-bucket capacity (mean 4224 + 13 sigma)

typedef unsigned short ushort_t;
typedef unsigned long long ull_t;
typedef __attribute__((ext_vector_type(8))) short short8;
typedef __attribute__((ext_vector_type(4))) float f32x4;

__device__ __forceinline__ unsigned short f32_to_bf16_rne(float x) {
    unsigned int v = __float_as_uint(x);
    unsigned int r = v + 0x7fffu + ((v >> 16) & 1u);
    return (unsigned short)(r >> 16);
}

// Two-phase dynamic partition, single edge read (reg-cached). Blocks >= T2
// do weight prep W (f32,[k][n]) -> Wp (bf16,[n][k]) for both layers.
__global__ __launch_bounds__(256) void k_part2(
    const int* __restrict__ src, const int* __restrict__ dst,
    int* __restrict__ cnt, unsigned int* __restrict__ pairs,
    int e, int nbp, int total, int T2,
    const float* __restrict__ W1, const float* __restrict__ W2,
    ushort_t* __restrict__ Wp1, ushort_t* __restrict__ Wp2) {
    int blk = blockIdx.x;
    int t = threadIdx.x;
    if (blk >= T2) {   // weight prep: 128 blocks cover 2*16384 elems
        int idx = (blk - T2) * 256 + t;
        int which = idx >> 14;
        int ee = idx & 16383;
        int n = ee & 127, k = ee >> 7;
        const float* W = which ? W2 : W1;
        ushort_t* Wp = which ? Wp2 : Wp1;
        Wp[n * 128 + k] = f32_to_bf16_rne(W[k * 128 + n]);
        return;
    }
    __shared__ int lcnt[NBMAX];
    __shared__ int lbase[NBMAX];
    int t0 = blk * PART_TILE2;
    for (int k = t; k < nbp; k += 256) lcnt[k] = 0;
    __syncthreads();
    int sv[EPT2], dvv[EPT2];
    // phase 1: load edges once, count per bucket
#pragma unroll
    for (int j = 0; j < EPT2; j++) {
        int i = t0 + j * 256 + t;
        if (i < total) {
            if (i < e) { sv[j] = src[i]; dvv[j] = dst[i]; }
            else       { sv[j] = i - e;  dvv[j] = sv[j]; }
            atomicAdd(&lcnt[dvv[j] >> 7], 1);
        } else {
            dvv[j] = -1;
        }
    }
    __syncthreads();
    // phase 2: reserve contiguous spans per bucket
    for (int k = t; k < nbp; k += 256) {
        int c = lcnt[k];
        lbase[k] = c ? atomicAdd(&cnt[k], c) : 0;
        lcnt[k] = 0;   // reuse as local cursor
    }
    __syncthreads();
    // phase 3: scatter from registers
#pragma unroll
    for (int j = 0; j < EPT2; j++) {
        if (dvv[j] >= 0) {
            int b = dvv[j] >> 7;
            int off = atomicAdd(&lcnt[b], 1) + lbase[b];
            pairs[(size_t)b * CAP + off] =
                (unsigned int)sv[j] | ((unsigned int)(dvv[j] & 127) << 17);
        }
    }
}

// One WG per bucket; LDS counts/scan -> row_se/dinv, fine-scatter into
// CAP-strided srcs (no global compaction -> no global scan needed).
__global__ __launch_bounds__(256) void k_build(
    const unsigned int* __restrict__ pairs, const int* __restrict__ cntg,
    ull_t* __restrict__ row_se, int* __restrict__ srcs,
    float* __restrict__ dinv, int n) {
    __shared__ int cnt[NPB];
    __shared__ int scn[NPB];
    __shared__ int cur[NPB];
    int b = blockIdx.x;
    int t = threadIdx.x;
    int node0 = b << 7;
    int cb = cntg[b];                       // pairs in this bucket
    int base = b * CAP;                     // srcs/pairs region base
    const unsigned int* bp = pairs + (size_t)base;
    if (t < NPB) cnt[t] = 0;
    __syncthreads();
    for (int i = t; i < cb; i += 256) {
        int dlow = (int)(bp[i] >> 17) & 127;
        atomicAdd(&cnt[dlow], 1);
    }
    __syncthreads();
    if (t < NPB) scn[t] = cnt[t];
    __syncthreads();
    for (int off = 1; off < NPB; off <<= 1) {
        int v = (t < NPB && t >= off) ? scn[t - off] : 0;
        __syncthreads();
        if (t < NPB) scn[t] += v;
        __syncthreads();
    }
    if (t < NPB) {
        int incl = scn[t];
        int excl = incl - cnt[t];
        cur[t] = excl;
        int node = node0 + t;
        if (node < n) {
            row_se[node] = (ull_t)(unsigned int)(base + excl) |
                           ((ull_t)(unsigned int)(base + incl) << 32);
            dinv[node] = rsqrtf((float)cnt[t]);  // deg >= 1 (self-loop)
        }
    }
    __syncthreads();
    int* bs = srcs + (size_t)base;
    for (int i = t; i < cb; i += 256) {
        unsigned int pr = bp[i];
        int pos = atomicAdd(&cur[(pr >> 17) & 127], 1);
        bs[pos] = (int)(pr & 0x1FFFFu);
    }
}

// ---------------------------------------------------------------------------
// GEMM1: G[ch][r][64] = bf16( dinv[r] * (A @ W)[r][ch*64..] ), A: Mx128 f32.
// 64-channel-chunk-major output ([2][M][64] bf16). Split-A bf16 MFMA.
// mfma_f32_16x16x32_bf16 layouts (HW-verified, guide m89/m91):
//   A: lane holds A[m=lane&15][k=(lane>>4)*8 + j]
//   B: lane holds B[k=(lane>>4)*8 + j][n=lane&15]   (Wp is [n][k] bf16)
//   C/D: col=lane&15, row=(lane>>4)*4 + reg
// Channel c*16+m lives in chunk c>>2 at offset (c&3)*16 + m.
// ---------------------------------------------------------------------------
__global__ __launch_bounds__(256) void k_gemm1(
    const float* __restrict__ A, const ushort_t* __restrict__ Wp,
    const float* __restrict__ dinv, ushort_t* __restrict__ G, int M) {
    int t = threadIdx.x;
    int row0 = blockIdx.x * 64;
    int wv = t >> 6;
    int lane = t & 63;
    int m = lane & 15;
    int quad = lane >> 4;

    int gr_row = row0 + wv * 16 + m;
    int gcl = gr_row < M ? gr_row : M - 1;
    const float* ap = A + (size_t)gcl * 128 + quad * 8;

    f32x4 acc[8];
#pragma unroll
    for (int c = 0; c < 8; c++) acc[c] = (f32x4){0.f, 0.f, 0.f, 0.f};

#pragma unroll
    for (int ks = 0; ks < 4; ks++) {
        int kb = ks * 32 + quad * 8;
        float xs[8];
        *(float4*)&xs[0] = *(const float4*)(ap + ks * 32);
        *(float4*)&xs[4] = *(const float4*)(ap + ks * 32 + 4);
        short8 ahi, alo;
#pragma unroll
        for (int j = 0; j < 8; j++) {
            unsigned short h = f32_to_bf16_rne(xs[j]);
            ahi[j] = (short)h;
            float hf = __uint_as_float((unsigned int)h << 16);
            alo[j] = (short)f32_to_bf16_rne(xs[j] - hf);
        }
#pragma unroll
        for (int c = 0; c < 8; c++) {
            short8 b8 = *(const short8*)(Wp + (size_t)(c * 16 + m) * 128 + kb);
            acc[c] = __builtin_amdgcn_mfma_f32_16x16x32_bf16(ahi, b8, acc[c], 0, 0, 0);
            acc[c] = __builtin_amdgcn_mfma_f32_16x16x32_bf16(alo, b8, acc[c], 0, 0, 0);
        }
    }

    int rbase = row0 + wv * 16 + quad * 4;
#pragma unroll
    for (int reg = 0; reg < 4; reg++) {
        int gr = rbase + reg;
        if (gr < M) {
            float dv = dinv[gr];
#pragma unroll
            for (int c = 0; c < 8; c++)
                G[((size_t)(c >> 2) * M + gr) * 64 + (c & 3) * 16 + m] =
                    f32_to_bf16_rne(acc[c][reg] * dv);
        }
    }
}

// ---------------------------------------------------------------------------
// GEMM2: in-place actG2[ch][r][64] = bf16( dinv[r] * (act @ W2)[r][..] ).
// act rows are wave-private (block = 64 rows, wave = 16 rows); in a wave all
// A-loads complete (MFMA data dep) before epilogue stores -> in-place is safe.
// Clamped tail rows may read racing data but their results are discarded.
// NOTE: actG2 deliberately NOT __restrict__ (true aliasing).
// ---------------------------------------------------------------------------
__global__ __launch_bounds__(256) void k_gemm2(
    ushort_t* actG2, const ushort_t* __restrict__ Wp,
    const float* __restrict__ dinv, int M) {
    int t = threadIdx.x;
    int row0 = blockIdx.x * 64;
    int wv = t >> 6;
    int lane = t & 63;
    int m = lane & 15;
    int quad = lane >> 4;

    int gr_row = row0 + wv * 16 + m;
    int gcl = gr_row < M ? gr_row : M - 1;

    f32x4 acc[8];
#pragma unroll
    for (int c = 0; c < 8; c++) acc[c] = (f32x4){0.f, 0.f, 0.f, 0.f};

#pragma unroll
    for (int ks = 0; ks < 4; ks++) {
        int kb = ks * 32 + quad * 8;
        // chunked act: channels kb..kb+7 live in chunk kb>>6 at offset kb&63
        short8 a8 = *(const short8*)(actG2 + ((size_t)(kb >> 6) * M + gcl) * 64 + (kb & 63));
#pragma unroll
        for (int c = 0; c < 8; c++) {
            short8 b8 = *(const short8*)(Wp + (size_t)(c * 16 + m) * 128 + kb);
            acc[c] = __builtin_amdgcn_mfma_f32_16x16x32_bf16(a8, b8, acc[c], 0, 0, 0);
        }
    }

    int rbase = row0 + wv * 16 + quad * 4;
#pragma unroll
    for (int reg = 0; reg < 4; reg++) {
        int gr = rbase + reg;
        if (gr < M) {
            float dv = dinv[gr];
#pragma unroll
            for (int c = 0; c < 8; c++)
                actG2[((size_t)(c >> 2) * M + gr) * 64 + (c & 3) * 16 + m] =
                    f32_to_bf16_rne(acc[c][reg] * dv);
        }
    }
}

// ---------------------------------------------------------------------------
// Aggregates: 2 XCD-parity chunk passes of 64 channels (chunk = bx&1,
// measured equal to sequential halves; misses are capacity-dominated).
// Each edge touches exactly ONE fully-used 128 B line. Wave = 4 nodes x
// 16 lanes (8 B/lane), serial exec-masked edge walk, unroll-4.
// srcs/row_se loads are NONTEMPORAL (read-once streams; keep L2 for table).
// ---------------------------------------------------------------------------

#define ACC_U(u)                                     \
    do {                                             \
        unsigned int ul_ = (unsigned int)(u);        \
        unsigned int uh_ = (unsigned int)((u) >> 32);\
        a0 += __uint_as_float(ul_ << 16);            \
        a1 += __uint_as_float(ul_ & 0xffff0000u);    \
        a2 += __uint_as_float(uh_ << 16);            \
        a3 += __uint_as_float(uh_ & 0xffff0000u);    \
    } while (0)

// Aggregate 1: act[chunk][node][64] = bf16(relu(dinv*sum(G1[src]) + b1)).
__global__ __launch_bounds__(256) void k_agg1(
    const ull_t* __restrict__ row_se, const int* __restrict__ srcs,
    const ushort_t* __restrict__ G, const float* __restrict__ dinv,
    const float* __restrict__ bias, ull_t* __restrict__ ActOut,
    int n) {
    int bx = blockIdx.x;
    int chunk = bx & 1;
    int tile = bx >> 1;
    int t = threadIdx.x;
    int lane = t & 63;
    int g = lane >> 4;     // node sub-index within wave (0..3)
    int q = lane & 15;     // 8 B quad within 64 channels
    int node = tile * 16 + (t >> 6) * 4 + g;
    bool valid = node < n;
    int nc = valid ? node : n - 1;
    ull_t se = __builtin_nontemporal_load(&row_se[nc]);
    int beg = (int)(unsigned int)se, end = (int)(unsigned int)(se >> 32);
    const ull_t* Tq = (const ull_t*)G + (size_t)chunk * n * 16 + q;
    float a0 = 0.f, a1 = 0.f, a2 = 0.f, a3 = 0.f;
    int e = beg;
    for (; e + 4 <= end; e += 4) {
        int s0 = __builtin_nontemporal_load(&srcs[e]);
        int s1 = __builtin_nontemporal_load(&srcs[e + 1]);
        int s2 = __builtin_nontemporal_load(&srcs[e + 2]);
        int s3 = __builtin_nontemporal_load(&srcs[e + 3]);
        ull_t u0 = Tq[(size_t)s0 * 16];
        ull_t u1 = Tq[(size_t)s1 * 16];
        ull_t u2 = Tq[(size_t)s2 * 16];
        ull_t u3 = Tq[(size_t)s3 * 16];
        ACC_U(u0); ACC_U(u1); ACC_U(u2); ACC_U(u3);
    }
    for (; e < end; ++e) {
        int s = __builtin_nontemporal_load(&srcs[e]);
        ull_t u = Tq[(size_t)s * 16];
        ACC_U(u);
    }
    if (valid) {
        float dv = dinv[node];
        const float* bp = bias + chunk * 64 + q * 4;
        a0 = fmaxf(fmaf(a0, dv, bp[0]), 0.f);
        a1 = fmaxf(fmaf(a1, dv, bp[1]), 0.f);
        a2 = fmaxf(fmaf(a2, dv, bp[2]), 0.f);
        a3 = fmaxf(fmaf(a3, dv, bp[3]), 0.f);
        unsigned int p0 = (unsigned int)f32_to_bf16_rne(a0) |
                          ((unsigned int)f32_to_bf16_rne(a1) << 16);
        unsigned int p1 = (unsigned int)f32_to_bf16_rne(a2) |
                          ((unsigned int)f32_to_bf16_rne(a3) << 16);
        ull_t uo = (ull_t)p0 | ((ull_t)p1 << 32);
        __builtin_nontemporal_store(uo, ActOut + ((size_t)chunk * n + node) * 16 + q);
    }
}

// Aggregate 2: out[node][chunk*64..] = dinv*sum(G2[src]) + b2 (f32, nt store).
__global__ __launch_bounds__(256) void k_agg2(
    const ull_t* __restrict__ row_se, const int* __restrict__ srcs,
    const ushort_t* __restrict__ G, const float* __restrict__ dinv,
    const float* __restrict__ bias, float* __restrict__ Out,
    int n) {
    int bx = blockIdx.x;
    int chunk = bx & 1;
    int tile = bx >> 1;
    int t = threadIdx.x;
    int lane = t & 63;
    int g = lane >> 4;
    int q = lane & 15;
    int node = tile * 16 + (t >> 6) * 4 + g;
    bool valid = node < n;
    int nc = valid ? node : n - 1;
    ull_t se = __builtin_nontemporal_load(&row_se[nc]);
    int beg = (int)(unsigned int)se, end = (int)(unsigned int)(se >> 32);
    const ull_t* Tq = (const ull_t*)G + (size_t)chunk * n * 16 + q;
    float a0 = 0.f, a1 = 0.f, a2 = 0.f, a3 = 0.f;
    int e = beg;
    for (; e + 4 <= end; e += 4) {
        int s0 = __builtin_nontemporal_load(&srcs[e]);
        int s1 = __builtin_nontemporal_load(&srcs[e + 1]);
        int s2 = __builtin_nontemporal_load(&srcs[e + 2]);
        int s3 = __builtin_nontemporal_load(&srcs[e + 3]);
        ull_t u0 = Tq[(size_t)s0 * 16];
        ull_t u1 = Tq[(size_t)s1 * 16];
        ull_t u2 = Tq[(size_t)s2 * 16];
        ull_t u3 = Tq[(size_t)s3 * 16];
        ACC_U(u0); ACC_U(u1); ACC_U(u2); ACC_U(u3);
    }
    for (; e < end; ++e) {
        int s = __builtin_nontemporal_load(&srcs[e]);
        ull_t u = Tq[(size_t)s * 16];
        ACC_U(u);
    }
    if (valid) {
        float dv = dinv[node];
        const float* bp = bias + chunk * 64 + q * 4;
        f32x4 o;
        o.x = fmaf(a0, dv, bp[0]);
        o.y = fmaf(a1, dv, bp[1]);
        o.z = fmaf(a2, dv, bp[2]);
        o.w = fmaf(a3, dv, bp[3]);
        __builtin_nontemporal_store(o,
            (f32x4*)(Out + (size_t)node * 128 + chunk * 64 + q * 4));
    }
}

extern "C" void kernel_launch(void* const* d_in, const int* in_sizes, int n_in,
                              void* d_out, int out_size, void* d_ws, size_t ws_size,
                              hipStream_t stream) {
    const float* x  = (const float*)d_in[0];
    const int*   ei = (const int*)d_in[1];
    const float* W1 = (const float*)d_in[2];
    const float* b1 = (const float*)d_in[3];
    const float* W2 = (const float*)d_in[4];
    const float* b2 = (const float*)d_in[5];
    float* out = (float*)d_out;

    const int C = 128;
    const int N = in_sizes[0] / C;
    const int E = in_sizes[1] / 2;
    const int* src = ei;
    const int* dst = ei + E;
    const int total = E + N;
    const int nbp = (N + NPB - 1) >> 7;                   // buckets (782)
    const int T2 = (total + PART_TILE2 - 1) / PART_TILE2; // tiles (~806)

    char* ws = (char*)d_ws;
    size_t off = 0;
    auto alloc = [&](size_t bytes) -> void* {
        void* p = ws + off;
        off = (off + bytes + 511) & ~(size_t)511;
        return p;
    };
    int*   cnt     = (int*)alloc((size_t)nbp * 4);
    ull_t* row_se  = (ull_t*)alloc((size_t)N * 8);
    float* dinv    = (float*)alloc((size_t)N * 4);
    int*   srcs    = (int*)alloc((size_t)nbp * CAP * 4);   // CAP-strided (16 MB)
    ushort_t* Wp1  = (ushort_t*)alloc(128 * 128 * 2);
    ushort_t* Wp2  = (ushort_t*)alloc(128 * 128 * 2);
    ushort_t* G1   = (ushort_t*)alloc((size_t)N * C * 2);
    // act/G2 (in-place, N*C*2 = 25.6 MB) shares with pairs (nbp*CAP*4 =
    // 16 MB): pairs dead after k_build, act written by k_agg1 afterwards.
    size_t ab = (size_t)N * C * 2, pb = (size_t)nbp * CAP * 4;
    void* shared = alloc(ab > pb ? ab : pb);
    ushort_t* actG2 = (ushort_t*)shared;
    unsigned int* pairs = (unsigned int*)shared;

    // ---- CSR build: partition(+wprep) -> build (no global scan) ----
    hipMemsetAsync(cnt, 0, (size_t)nbp * 4, stream);
    k_part2<<<T2 + 128, 256, 0, stream>>>(src, dst, cnt, pairs, E, nbp, total,
                                          T2, W1, W2, Wp1, Wp2);
    k_build<<<nbp, 256, 0, stream>>>(pairs, cnt, row_se, srcs, dinv, N);

    // agg grid: chunk = bx&1 (XCD parity), tile = bx>>1; 16 nodes/block
    const int half = (N + 15) / 16;
    dim3 agrid(half * 2);

    // ---- layer 1: G1[ch][r][64] = bf16(dinv*(x@W1)); act chunked bf16 ----
    k_gemm1<<<(N + 63) / 64, 256, 0, stream>>>(x, Wp1, dinv, G1, N);
    k_agg1<<<agrid, 256, 0, stream>>>(row_se, srcs, G1, dinv, b1,
                                      (ull_t*)actG2, N);

    // ---- layer 2: G2 = bf16(dinv*(act@W2)) in-place chunked; out ----
    k_gemm2<<<(N + 63) / 64, 256, 0, stream>>>(actG2, Wp2, dinv, N);
    k_agg2<<<agrid, 256, 0, stream>>>(row_se, srcs, actG2, dinv, b2, out, N);
}

// Round 12
// 453.840 us; speedup vs baseline: 1.1270x; 1.1270x over previous
//
#include <hip/hip_runtime.h>

// ---------------------------------------------------------------------------
// 2-layer GCN: out = A_norm @ relu(A_norm @ (x@W1) + b1) @ W2 (+b2)
// A_norm = D^-1/2 (A+I) D^-1/2, factored: out[d] = dinv[d]*sum_src(g[src]) + b
// with g = dinv * (x @ W).
//
// R7: 519. R11: 64-ch chunk aggregates [2][N][64] bf16, 509.
// R13: two-phase partition CSR, 495.8. R14: XCD pinning null (capacity-
//      dominated misses). R15: consolidation (srcs CAP-strided, row_se u64,
//      no global scan, wprep folded, single-read partition) = middle
//      286->238 us (GOOD); but nt loads on srcs = agg 104.8->137,
//      FETCH +80 MB (BAD): srcs lines are read ~16x (serial element walk),
//      nt evicts after first touch -> line re-fetch per element. Lesson:
//      nt hints only for line-once streams.
// R16: R15 structure + plain loads for srcs/row_se (nt kept only on
//      true write-once outputs). Expect aggs ~104 us + middle ~238.
// Requires N <= 131072 (17-bit src in packed pairs).
// ---------------------------------------------------------------------------

#define NPB 128          // nodes per bucket (dst >> 7)
#define NBMAX 1024       // supports N <= 131072
#define EPT2 16          // edges per thread in partition kernel
#define PART_TILE2 (256 * EPT2)
#define CAP 5120         // per-bucket capacity (mean 4224 + 13 sigma)

typedef unsigned short ushort_t;
typedef unsigned long long ull_t;
typedef __attribute__((ext_vector_type(8))) short short8;
typedef __attribute__((ext_vector_type(4))) float f32x4;

__device__ __forceinline__ unsigned short f32_to_bf16_rne(float x) {
    unsigned int v = __float_as_uint(x);
    unsigned int r = v + 0x7fffu + ((v >> 16) & 1u);
    return (unsigned short)(r >> 16);
}

// Two-phase dynamic partition, single edge read (reg-cached). Blocks >= T2
// do weight prep W (f32,[k][n]) -> Wp (bf16,[n][k]) for both layers.
__global__ __launch_bounds__(256) void k_part2(
    const int* __restrict__ src, const int* __restrict__ dst,
    int* __restrict__ cnt, unsigned int* __restrict__ pairs,
    int e, int nbp, int total, int T2,
    const float* __restrict__ W1, const float* __restrict__ W2,
    ushort_t* __restrict__ Wp1, ushort_t* __restrict__ Wp2) {
    int blk = blockIdx.x;
    int t = threadIdx.x;
    if (blk >= T2) {   // weight prep: 128 blocks cover 2*16384 elems
        int idx = (blk - T2) * 256 + t;
        int which = idx >> 14;
        int ee = idx & 16383;
        int n = ee & 127, k = ee >> 7;
        const float* W = which ? W2 : W1;
        ushort_t* Wp = which ? Wp2 : Wp1;
        Wp[n * 128 + k] = f32_to_bf16_rne(W[k * 128 + n]);
        return;
    }
    __shared__ int lcnt[NBMAX];
    __shared__ int lbase[NBMAX];
    int t0 = blk * PART_TILE2;
    for (int k = t; k < nbp; k += 256) lcnt[k] = 0;
    __syncthreads();
    int sv[EPT2], dvv[EPT2];
    // phase 1: load edges once, count per bucket
#pragma unroll
    for (int j = 0; j < EPT2; j++) {
        int i = t0 + j * 256 + t;
        if (i < total) {
            if (i < e) { sv[j] = src[i]; dvv[j] = dst[i]; }
            else       { sv[j] = i - e;  dvv[j] = sv[j]; }
            atomicAdd(&lcnt[dvv[j] >> 7], 1);
        } else {
            dvv[j] = -1;
        }
    }
    __syncthreads();
    // phase 2: reserve contiguous spans per bucket
    for (int k = t; k < nbp; k += 256) {
        int c = lcnt[k];
        lbase[k] = c ? atomicAdd(&cnt[k], c) : 0;
        lcnt[k] = 0;   // reuse as local cursor
    }
    __syncthreads();
    // phase 3: scatter from registers
#pragma unroll
    for (int j = 0; j < EPT2; j++) {
        if (dvv[j] >= 0) {
            int b = dvv[j] >> 7;
            int off = atomicAdd(&lcnt[b], 1) + lbase[b];
            pairs[(size_t)b * CAP + off] =
                (unsigned int)sv[j] | ((unsigned int)(dvv[j] & 127) << 17);
        }
    }
}

// One WG per bucket; LDS counts/scan -> row_se/dinv, fine-scatter into
// CAP-strided srcs (no global compaction -> no global scan needed).
__global__ __launch_bounds__(256) void k_build(
    const unsigned int* __restrict__ pairs, const int* __restrict__ cntg,
    ull_t* __restrict__ row_se, int* __restrict__ srcs,
    float* __restrict__ dinv, int n) {
    __shared__ int cnt[NPB];
    __shared__ int scn[NPB];
    __shared__ int cur[NPB];
    int b = blockIdx.x;
    int t = threadIdx.x;
    int node0 = b << 7;
    int cb = cntg[b];                       // pairs in this bucket
    int base = b * CAP;                     // srcs/pairs region base
    const unsigned int* bp = pairs + (size_t)base;
    if (t < NPB) cnt[t] = 0;
    __syncthreads();
    for (int i = t; i < cb; i += 256) {
        int dlow = (int)(bp[i] >> 17) & 127;
        atomicAdd(&cnt[dlow], 1);
    }
    __syncthreads();
    if (t < NPB) scn[t] = cnt[t];
    __syncthreads();
    for (int off = 1; off < NPB; off <<= 1) {
        int v = (t < NPB && t >= off) ? scn[t - off] : 0;
        __syncthreads();
        if (t < NPB) scn[t] += v;
        __syncthreads();
    }
    if (t < NPB) {
        int incl = scn[t];
        int excl = incl - cnt[t];
        cur[t] = excl;
        int node = node0 + t;
        if (node < n) {
            row_se[node] = (ull_t)(unsigned int)(base + excl) |
                           ((ull_t)(unsigned int)(base + incl) << 32);
            dinv[node] = rsqrtf((float)cnt[t]);  // deg >= 1 (self-loop)
        }
    }
    __syncthreads();
    int* bs = srcs + (size_t)base;
    for (int i = t; i < cb; i += 256) {
        unsigned int pr = bp[i];
        int pos = atomicAdd(&cur[(pr >> 17) & 127], 1);
        bs[pos] = (int)(pr & 0x1FFFFu);
    }
}

// ---------------------------------------------------------------------------
// GEMM1: G[ch][r][64] = bf16( dinv[r] * (A @ W)[r][ch*64..] ), A: Mx128 f32.
// 64-channel-chunk-major output ([2][M][64] bf16). Split-A bf16 MFMA.
// mfma_f32_16x16x32_bf16 layouts (HW-verified, guide m89/m91):
//   A: lane holds A[m=lane&15][k=(lane>>4)*8 + j]
//   B: lane holds B[k=(lane>>4)*8 + j][n=lane&15]   (Wp is [n][k] bf16)
//   C/D: col=lane&15, row=(lane>>4)*4 + reg
// Channel c*16+m lives in chunk c>>2 at offset (c&3)*16 + m.
// ---------------------------------------------------------------------------
__global__ __launch_bounds__(256) void k_gemm1(
    const float* __restrict__ A, const ushort_t* __restrict__ Wp,
    const float* __restrict__ dinv, ushort_t* __restrict__ G, int M) {
    int t = threadIdx.x;
    int row0 = blockIdx.x * 64;
    int wv = t >> 6;
    int lane = t & 63;
    int m = lane & 15;
    int quad = lane >> 4;

    int gr_row = row0 + wv * 16 + m;
    int gcl = gr_row < M ? gr_row : M - 1;
    const float* ap = A + (size_t)gcl * 128 + quad * 8;

    f32x4 acc[8];
#pragma unroll
    for (int c = 0; c < 8; c++) acc[c] = (f32x4){0.f, 0.f, 0.f, 0.f};

#pragma unroll
    for (int ks = 0; ks < 4; ks++) {
        int kb = ks * 32 + quad * 8;
        float xs[8];
        *(float4*)&xs[0] = *(const float4*)(ap + ks * 32);
        *(float4*)&xs[4] = *(const float4*)(ap + ks * 32 + 4);
        short8 ahi, alo;
#pragma unroll
        for (int j = 0; j < 8; j++) {
            unsigned short h = f32_to_bf16_rne(xs[j]);
            ahi[j] = (short)h;
            float hf = __uint_as_float((unsigned int)h << 16);
            alo[j] = (short)f32_to_bf16_rne(xs[j] - hf);
        }
#pragma unroll
        for (int c = 0; c < 8; c++) {
            short8 b8 = *(const short8*)(Wp + (size_t)(c * 16 + m) * 128 + kb);
            acc[c] = __builtin_amdgcn_mfma_f32_16x16x32_bf16(ahi, b8, acc[c], 0, 0, 0);
            acc[c] = __builtin_amdgcn_mfma_f32_16x16x32_bf16(alo, b8, acc[c], 0, 0, 0);
        }
    }

    int rbase = row0 + wv * 16 + quad * 4;
#pragma unroll
    for (int reg = 0; reg < 4; reg++) {
        int gr = rbase + reg;
        if (gr < M) {
            float dv = dinv[gr];
#pragma unroll
            for (int c = 0; c < 8; c++)
                G[((size_t)(c >> 2) * M + gr) * 64 + (c & 3) * 16 + m] =
                    f32_to_bf16_rne(acc[c][reg] * dv);
        }
    }
}

// ---------------------------------------------------------------------------
// GEMM2: in-place actG2[ch][r][64] = bf16( dinv[r] * (act @ W2)[r][..] ).
// act rows are wave-private (block = 64 rows, wave = 16 rows); in a wave all
// A-loads complete (MFMA data dep) before epilogue stores -> in-place is safe.
// Clamped tail rows may read racing data but their results are discarded.
// NOTE: actG2 deliberately NOT __restrict__ (true aliasing).
// ---------------------------------------------------------------------------
__global__ __launch_bounds__(256) void k_gemm2(
    ushort_t* actG2, const ushort_t* __restrict__ Wp,
    const float* __restrict__ dinv, int M) {
    int t = threadIdx.x;
    int row0 = blockIdx.x * 64;
    int wv = t >> 6;
    int lane = t & 63;
    int m = lane & 15;
    int quad = lane >> 4;

    int gr_row = row0 + wv * 16 + m;
    int gcl = gr_row < M ? gr_row : M - 1;

    f32x4 acc[8];
#pragma unroll
    for (int c = 0; c < 8; c++) acc[c] = (f32x4){0.f, 0.f, 0.f, 0.f};

#pragma unroll
    for (int ks = 0; ks < 4; ks++) {
        int kb = ks * 32 + quad * 8;
        // chunked act: channels kb..kb+7 live in chunk kb>>6 at offset kb&63
        short8 a8 = *(const short8*)(actG2 + ((size_t)(kb >> 6) * M + gcl) * 64 + (kb & 63));
#pragma unroll
        for (int c = 0; c < 8; c++) {
            short8 b8 = *(const short8*)(Wp + (size_t)(c * 16 + m) * 128 + kb);
            acc[c] = __builtin_amdgcn_mfma_f32_16x16x32_bf16(a8, b8, acc[c], 0, 0, 0);
        }
    }

    int rbase = row0 + wv * 16 + quad * 4;
#pragma unroll
    for (int reg = 0; reg < 4; reg++) {
        int gr = rbase + reg;
        if (gr < M) {
            float dv = dinv[gr];
#pragma unroll
            for (int c = 0; c < 8; c++)
                actG2[((size_t)(c >> 2) * M + gr) * 64 + (c & 3) * 16 + m] =
                    f32_to_bf16_rne(acc[c][reg] * dv);
        }
    }
}

// ---------------------------------------------------------------------------
// Aggregates: 2 XCD-parity chunk passes of 64 channels (chunk = bx&1).
// Each edge touches exactly ONE fully-used 128 B line. Wave = 4 nodes x
// 16 lanes (8 B/lane), serial exec-masked edge walk, unroll-4.
// Plain (cached) loads for srcs/row_se: srcs lines serve ~16 consecutive
// elements (R15 lesson: nt loads here re-fetch the line per element).
// ---------------------------------------------------------------------------

#define ACC_U(u)                                     \
    do {                                             \
        unsigned int ul_ = (unsigned int)(u);        \
        unsigned int uh_ = (unsigned int)((u) >> 32);\
        a0 += __uint_as_float(ul_ << 16);            \
        a1 += __uint_as_float(ul_ & 0xffff0000u);    \
        a2 += __uint_as_float(uh_ << 16);            \
        a3 += __uint_as_float(uh_ & 0xffff0000u);    \
    } while (0)

// Aggregate 1: act[chunk][node][64] = bf16(relu(dinv*sum(G1[src]) + b1)).
__global__ __launch_bounds__(256) void k_agg1(
    const ull_t* __restrict__ row_se, const int* __restrict__ srcs,
    const ushort_t* __restrict__ G, const float* __restrict__ dinv,
    const float* __restrict__ bias, ull_t* __restrict__ ActOut,
    int n) {
    int bx = blockIdx.x;
    int chunk = bx & 1;
    int tile = bx >> 1;
    int t = threadIdx.x;
    int lane = t & 63;
    int g = lane >> 4;     // node sub-index within wave (0..3)
    int q = lane & 15;     // 8 B quad within 64 channels
    int node = tile * 16 + (t >> 6) * 4 + g;
    bool valid = node < n;
    int nc = valid ? node : n - 1;
    ull_t se = row_se[nc];
    int beg = (int)(unsigned int)se, end = (int)(unsigned int)(se >> 32);
    const ull_t* Tq = (const ull_t*)G + (size_t)chunk * n * 16 + q;
    float a0 = 0.f, a1 = 0.f, a2 = 0.f, a3 = 0.f;
    int e = beg;
    for (; e + 4 <= end; e += 4) {
        int s0 = srcs[e], s1 = srcs[e + 1], s2 = srcs[e + 2], s3 = srcs[e + 3];
        ull_t u0 = Tq[(size_t)s0 * 16];
        ull_t u1 = Tq[(size_t)s1 * 16];
        ull_t u2 = Tq[(size_t)s2 * 16];
        ull_t u3 = Tq[(size_t)s3 * 16];
        ACC_U(u0); ACC_U(u1); ACC_U(u2); ACC_U(u3);
    }
    for (; e < end; ++e) {
        int s = srcs[e];
        ull_t u = Tq[(size_t)s * 16];
        ACC_U(u);
    }
    if (valid) {
        float dv = dinv[node];
        const float* bp = bias + chunk * 64 + q * 4;
        a0 = fmaxf(fmaf(a0, dv, bp[0]), 0.f);
        a1 = fmaxf(fmaf(a1, dv, bp[1]), 0.f);
        a2 = fmaxf(fmaf(a2, dv, bp[2]), 0.f);
        a3 = fmaxf(fmaf(a3, dv, bp[3]), 0.f);
        unsigned int p0 = (unsigned int)f32_to_bf16_rne(a0) |
                          ((unsigned int)f32_to_bf16_rne(a1) << 16);
        unsigned int p1 = (unsigned int)f32_to_bf16_rne(a2) |
                          ((unsigned int)f32_to_bf16_rne(a3) << 16);
        ull_t uo = (ull_t)p0 | ((ull_t)p1 << 32);
        __builtin_nontemporal_store(uo, ActOut + ((size_t)chunk * n + node) * 16 + q);
    }
}

// Aggregate 2: out[node][chunk*64..] = dinv*sum(G2[src]) + b2 (f32, nt store).
__global__ __launch_bounds__(256) void k_agg2(
    const ull_t* __restrict__ row_se, const int* __restrict__ srcs,
    const ushort_t* __restrict__ G, const float* __restrict__ dinv,
    const float* __restrict__ bias, float* __restrict__ Out,
    int n) {
    int bx = blockIdx.x;
    int chunk = bx & 1;
    int tile = bx >> 1;
    int t = threadIdx.x;
    int lane = t & 63;
    int g = lane >> 4;
    int q = lane & 15;
    int node = tile * 16 + (t >> 6) * 4 + g;
    bool valid = node < n;
    int nc = valid ? node : n - 1;
    ull_t se = row_se[nc];
    int beg = (int)(unsigned int)se, end = (int)(unsigned int)(se >> 32);
    const ull_t* Tq = (const ull_t*)G + (size_t)chunk * n * 16 + q;
    float a0 = 0.f, a1 = 0.f, a2 = 0.f, a3 = 0.f;
    int e = beg;
    for (; e + 4 <= end; e += 4) {
        int s0 = srcs[e], s1 = srcs[e + 1], s2 = srcs[e + 2], s3 = srcs[e + 3];
        ull_t u0 = Tq[(size_t)s0 * 16];
        ull_t u1 = Tq[(size_t)s1 * 16];
        ull_t u2 = Tq[(size_t)s2 * 16];
        ull_t u3 = Tq[(size_t)s3 * 16];
        ACC_U(u0); ACC_U(u1); ACC_U(u2); ACC_U(u3);
    }
    for (; e < end; ++e) {
        int s = srcs[e];
        ull_t u = Tq[(size_t)s * 16];
        ACC_U(u);
    }
    if (valid) {
        float dv = dinv[node];
        const float* bp = bias + chunk * 64 + q * 4;
        f32x4 o;
        o.x = fmaf(a0, dv, bp[0]);
        o.y = fmaf(a1, dv, bp[1]);
        o.z = fmaf(a2, dv, bp[2]);
        o.w = fmaf(a3, dv, bp[3]);
        __builtin_nontemporal_store(o,
            (f32x4*)(Out + (size_t)node * 128 + chunk * 64 + q * 4));
    }
}

extern "C" void kernel_launch(void* const* d_in, const int* in_sizes, int n_in,
                              void* d_out, int out_size, void* d_ws, size_t ws_size,
                              hipStream_t stream) {
    const float* x  = (const float*)d_in[0];
    const int*   ei = (const int*)d_in[1];
    const float* W1 = (const float*)d_in[2];
    const float* b1 = (const float*)d_in[3];
    const float* W2 = (const float*)d_in[4];
    const float* b2 = (const float*)d_in[5];
    float* out = (float*)d_out;

    const int C = 128;
    const int N = in_sizes[0] / C;
    const int E = in_sizes[1] / 2;
    const int* src = ei;
    const int* dst = ei + E;
    const int total = E + N;
    const int nbp = (N + NPB - 1) >> 7;                   // buckets (782)
    const int T2 = (total + PART_TILE2 - 1) / PART_TILE2; // tiles (~806)

    char* ws = (char*)d_ws;
    size_t off = 0;
    auto alloc = [&](size_t bytes) -> void* {
        void* p = ws + off;
        off = (off + bytes + 511) & ~(size_t)511;
        return p;
    };
    int*   cnt     = (int*)alloc((size_t)nbp * 4);
    ull_t* row_se  = (ull_t*)alloc((size_t)N * 8);
    float* dinv    = (float*)alloc((size_t)N * 4);
    int*   srcs    = (int*)alloc((size_t)nbp * CAP * 4);   // CAP-strided (16 MB)
    ushort_t* Wp1  = (ushort_t*)alloc(128 * 128 * 2);
    ushort_t* Wp2  = (ushort_t*)alloc(128 * 128 * 2);
    ushort_t* G1   = (ushort_t*)alloc((size_t)N * C * 2);
    // act/G2 (in-place, N*C*2 = 25.6 MB) shares with pairs (nbp*CAP*4 =
    // 16 MB): pairs dead after k_build, act written by k_agg1 afterwards.
    size_t ab = (size_t)N * C * 2, pb = (size_t)nbp * CAP * 4;
    void* shared = alloc(ab > pb ? ab : pb);
    ushort_t* actG2 = (ushort_t*)shared;
    unsigned int* pairs = (unsigned int*)shared;

    // ---- CSR build: partition(+wprep) -> build (no global scan) ----
    hipMemsetAsync(cnt, 0, (size_t)nbp * 4, stream);
    k_part2<<<T2 + 128, 256, 0, stream>>>(src, dst, cnt, pairs, E, nbp, total,
                                          T2, W1, W2, Wp1, Wp2);
    k_build<<<nbp, 256, 0, stream>>>(pairs, cnt, row_se, srcs, dinv, N);

    // agg grid: chunk = bx&1 (XCD parity), tile = bx>>1; 16 nodes/block
    const int half = (N + 15) / 16;
    dim3 agrid(half * 2);

    // ---- layer 1: G1[ch][r][64] = bf16(dinv*(x@W1)); act chunked bf16 ----
    k_gemm1<<<(N + 63) / 64, 256, 0, stream>>>(x, Wp1, dinv, G1, N);
    k_agg1<<<agrid, 256, 0, stream>>>(row_se, srcs, G1, dinv, b1,
                                      (ull_t*)actG2, N);

    // ---- layer 2: G2 = bf16(dinv*(act@W2)) in-place chunked; out ----
    k_gemm2<<<(N + 63) / 64, 256, 0, stream>>>(actG2, Wp2, dinv, N);
    k_agg2<<<agrid, 256, 0, stream>>>(row_se, srcs, actG2, dinv, b2, out, N);
}